// Round 5
// baseline (1770.965 us; speedup 1.0000x reference)
//
#include <hip/hip_runtime.h>
#include <hip/hip_bf16.h>
#include <cstdint>

// Problem constants
// B=16, N=4096, S=1024 (NPOINT), K=32 (NSAMPLE), CIN=64, MLP 67->64->64->128
// M = B*S*K = 524288 rows through the MLP.

typedef __attribute__((ext_vector_type(8))) short bf16x8;
typedef __attribute__((ext_vector_type(4))) float f32x4;

#define LDA 104   // bf16 LDS row stride: 208 B = 52 dwords -> 2-way (free) b128 bank pattern

__device__ __forceinline__ unsigned short f2bf(float f) {
  unsigned x = __float_as_uint(f);
  unsigned r = (x + 0x7FFFu + ((x >> 16) & 1u)) >> 16;  // RNE
  return (unsigned short)r;
}
__device__ __forceinline__ float bf2f(unsigned short u) {
  return __uint_as_float(((unsigned)u) << 16);
}

// DPP max-combine on a packed 64-bit key. DPP row ops are VALU-latency (~2-4cyc)
// vs ~120cyc for ds_permute-backed __shfl — this is the FPS critical path.
template <int CTRL>
__device__ __forceinline__ unsigned long long dppmax(unsigned long long k) {
  int lo = (int)(unsigned)k;
  int hi = (int)(unsigned)(k >> 32);
  int plo = __builtin_amdgcn_update_dpp(lo, lo, CTRL, 0xF, 0xF, false);
  int phi = __builtin_amdgcn_update_dpp(hi, hi, CTRL, 0xF, 0xF, false);
  unsigned long long o =
      ((unsigned long long)(unsigned)phi << 32) | (unsigned)plo;
  return (o > k) ? o : k;
}

// ---------------------------------------------------------------------------
// Fused FPS + prep, 256 threads/block. Blocks 0..15: FPS (one per batch).
// Blocks 16..1039: points transpose. Block 1040: weight tiles + stats zero.
//
// REGISTER-BUDGET NOTE (rounds 3/4 regression root cause): the FPS path keeps
// px/py/pz/dist[16] = 64 floats in registers. The AMDGPU allocator's VGPR
// budget is derived from an occupancy heuristic that we could NOT override
// with __launch_bounds__(.,1) (round 4: still spilled, VGPR_Count=36,
// 2023 cyc/iter from scratch reloads in the serial chain). The only measured
// no-spill config is 256 thr + ~50KB LDS (round 2: VGPR=68): big LDS caps
// occupancy at ~3 blocks/CU -> waves/EU target ~3 -> VGPR budget ~170.
// smraw is therefore INTENTIONALLY oversized to 50176 B. Only 16 FPS blocks
// (and transient prep blocks) exist; 240 CUs idle regardless, so the
// occupancy cost is nil and the register budget is protected.
//
// FPS per-iter serial chain: VALU dist-update (winner coords carried via
// cndmask) -> DPP wave argmax (packed 64b key) -> readlane(63) -> owner lane
// writes {key,x,y,z} slot (double-buffered) -> ONE barrier -> all threads
// combine 4 slots (uniform). NO global stores in the loop (they force a
// vmcnt(0) drain at the barrier — measured ~500 cyc/iter in round 2);
// centers buffered in LDS, written coalesced at the end.
// Index selection bit-identical to numpy (max dist, tie -> min n, via
// key = bits(dist)<<32 | ~n).
// ---------------------------------------------------------------------------
__global__ __launch_bounds__(256) void fps_prep_kernel(
    const float* __restrict__ xyz, const float* __restrict__ points,
    const float* __restrict__ W0, const float* __restrict__ W1,
    const float* __restrict__ W2, unsigned short* __restrict__ pT,
    unsigned short* __restrict__ w0t, unsigned short* __restrict__ w1t,
    unsigned short* __restrict__ w2t, float* __restrict__ stats_all,
    float* __restrict__ out, float4* __restrict__ centers4)
{
  __shared__ __align__(16) char smraw[50176];   // oversized on purpose, see note
  int tid = threadIdx.x;
  if (blockIdx.x >= 16) {
    int pb = blockIdx.x - 16;
    if (pb < 1024) {
      float (*tile)[65] = (float (*)[65])smraw;
      int b = pb >> 6;
      int n0 = (pb & 63) << 6;
      const float* pbp = points + ((size_t)b << 18);
      for (int i = tid; i < 4096; i += 256) {
        int cc = i >> 6, nn = i & 63;
        tile[cc][nn] = pbp[((size_t)cc << 12) + n0 + nn];
      }
      __syncthreads();
      for (int i = tid; i < 4096; i += 256) {
        int nn = i >> 6, cc = i & 63;
        pT[(((size_t)((b << 12) + n0 + nn)) << 6) + cc] = f2bf(tile[cc][nn]);
      }
    } else {
      // w0t: 64x104, w1t: 64x104, w2t: 128x104, stats: 512 floats
      for (int i = tid; i < 27136; i += 256) {
        if (i < 6656) {
          int nn = i / 104, kk = i % 104;
          float v = (kk < 64) ? W0[(3 + kk) * 64 + nn]
                              : ((kk < 67) ? W0[(kk - 64) * 64 + nn] : 0.f);
          w0t[i] = f2bf(v);
        } else if (i < 13312) {
          int j = i - 6656; int nn = j / 104, kk = j % 104;
          float v = (kk < 64) ? W1[kk * 64 + nn] : 0.f;
          w1t[j] = f2bf(v);
        } else if (i < 26624) {
          int j = i - 13312; int nn = j / 104, kk = j % 104;
          float v = (kk < 64) ? W2[kk * 128 + nn] : 0.f;
          w2t[j] = f2bf(v);
        } else {
          stats_all[i - 26624] = 0.f;
        }
      }
    }
    return;
  }
  // ---- FPS path ----
  float* cxl = (float*)smraw;                       // [1024]
  float* cyl = (float*)(smraw + 4096);              // [1024]
  float* czl = (float*)(smraw + 8192);              // [1024]
  unsigned long long (*skey)[4] =
      (unsigned long long (*)[4])(smraw + 12288);   // [2][4]
  float4 (*scoord)[4] = (float4 (*)[4])(smraw + 12352);  // [2][4]

  int b = blockIdx.x;
  const float* xb = xyz + (size_t)b * 12288;
  float px[16], py[16], pz[16], dist[16];
#pragma unroll
  for (int j = 0; j < 16; ++j) {
    int n = tid + (j << 8);
    px[j] = xb[n]; py[j] = xb[4096 + n]; pz[j] = xb[8192 + n];
    dist[j] = 1e10f;
  }
  float cx = xb[0], cy = xb[4096], cz = xb[8192];
  if (tid == 0) { cxl[0] = cx; cyl[0] = cy; czl[0] = cz; }
  int w = tid >> 6;
  for (int it = 1; it < 1024; ++it) {
    float bv = -1.f; int bi = 0;
    float bx = 0.f, by = 0.f, bz = 0.f;
#pragma unroll
    for (int j = 0; j < 16; ++j) {
      float dx = __fsub_rn(px[j], cx);
      float dy = __fsub_rn(py[j], cy);
      float dz = __fsub_rn(pz[j], cz);
      float d  = __fadd_rn(__fadd_rn(__fmul_rn(dx, dx), __fmul_rn(dy, dy)),
                           __fmul_rn(dz, dz));
      float nd = fminf(dist[j], d);
      dist[j] = nd;
      if (nd > bv) {   // strict >, j asc => first occurrence (min n)
        bv = nd; bi = tid + (j << 8);
        bx = px[j]; by = py[j]; bz = pz[j];
      }
    }
    // pack: high 32 = dist bits (nonneg float => monotone), low 32 = ~n
    unsigned long long key0 =
        ((unsigned long long)__float_as_uint(bv) << 32) | (unsigned)(~bi);
    unsigned long long k = key0;
    k = dppmax<0xB1>(k);    // quad_perm [1,0,3,2]  : xor 1
    k = dppmax<0x4E>(k);    // quad_perm [2,3,0,1]  : xor 2
    k = dppmax<0x141>(k);   // row_half_mirror      : xor 4
    k = dppmax<0x140>(k);   // row_mirror           : xor 8
    k = dppmax<0x142>(k);   // row_bcast15          : rows 0->1, 2->3
    k = dppmax<0x143>(k);   // row_bcast31          : rows 01 -> 23
    unsigned wk_lo = (unsigned)__builtin_amdgcn_readlane((int)(unsigned)k, 63);
    unsigned wk_hi = (unsigned)__builtin_amdgcn_readlane((int)(unsigned)(k >> 32), 63);
    unsigned long long wk = ((unsigned long long)wk_hi << 32) | wk_lo;
    int p = it & 1;
    if (key0 == wk) {                 // unique owner lane per wave
      skey[p][w]   = wk;
      scoord[p][w] = make_float4(bx, by, bz, 0.f);
    }
    __syncthreads();
    unsigned long long ka = skey[p][0]; float4 ca = scoord[p][0];
    {
      unsigned long long k1 = skey[p][1]; float4 c1 = scoord[p][1];
      if (k1 > ka) { ka = k1; ca = c1; }
      unsigned long long k2 = skey[p][2]; float4 c2 = scoord[p][2];
      if (k2 > ka) { ka = k2; ca = c2; }
      unsigned long long k3 = skey[p][3]; float4 c3 = scoord[p][3];
      if (k3 > ka) { ka = k3; ca = c3; }
    }
    cx = ca.x; cy = ca.y; cz = ca.z;
    if (tid == 0) { cxl[it] = cx; cyl[it] = cy; czl[it] = cz; }
    // no second barrier: next iter writes slot[(it+1)&1], disjoint slot;
    // a wave re-writes this slot only after passing the NEXT barrier, which
    // orders it after every wave's read above.
  }
  __syncthreads();
  for (int it = tid; it < 1024; it += 256) {
    float x = cxl[it], y = cyl[it], z = czl[it];
    out[b * 3072 + it]        = x;
    out[b * 3072 + 1024 + it] = y;
    out[b * 3072 + 2048 + it] = z;
    centers4[(b << 10) + it]  = make_float4(x, y, z, 0.f);
  }
}

// ---------------------------------------------------------------------------
// Ball query: thread = center; scan n ascending, first <=32 hits, early exit.
// ---------------------------------------------------------------------------
__global__ __launch_bounds__(256) void ball_kernel(const float* __restrict__ xyz,
                                                   const float4* __restrict__ centers4,
                                                   int* __restrict__ ballidx)
{
  __shared__ float xs[4096], ys[4096], zs[4096];
  int b = blockIdx.x >> 2, tid = threadIdx.x;
  int s = ((blockIdx.x & 3) << 8) + tid;
  const float* xb = xyz + (size_t)b * 12288;
  for (int i = tid; i < 4096; i += 256) {
    xs[i] = xb[i]; ys[i] = xb[4096 + i]; zs[i] = xb[8192 + i];
  }
  __syncthreads();
  float4 c = centers4[(b << 10) + s];
  int* ob = ballidx + (((size_t)((b << 10) + s)) << 5);
  int cnt = 0, first = 0;
  for (int n = 0; n < 4096; ++n) {
    if (cnt < 32) {
      float dx = __fsub_rn(xs[n], c.x);
      float dy = __fsub_rn(ys[n], c.y);
      float dz = __fsub_rn(zs[n], c.z);
      float d  = __fadd_rn(__fadd_rn(__fmul_rn(dx, dx), __fmul_rn(dy, dy)),
                           __fmul_rn(dz, dz));
      if (!(d > 0.04f)) {        // 0.04f == f32(RADIUS**2), matches ref compare
        if (cnt == 0) first = n;
        ob[cnt] = n; ++cnt;
      }
    }
    if (__all(cnt >= 32)) break;
  }
  for (int k = cnt; k < 32; ++k) ob[k] = first;
}

// ---------------------------------------------------------------------------
// GEMM1: gather (pT rows + g_xyz) -> A[64 x 96(pad104)] bf16, W'T0, MFMA,
// write raw y1 bf16 [M,64] + per-block channel partials (sum, sumsq).
// ---------------------------------------------------------------------------
__global__ __launch_bounds__(256) void gemm1_kernel(
    const float* __restrict__ xyz, const unsigned short* __restrict__ pT,
    const unsigned short* __restrict__ w0t, const float* __restrict__ b0,
    const float4* __restrict__ centers4, const int* __restrict__ ballidx,
    unsigned short* __restrict__ feats1, float* __restrict__ partials)
{
  __shared__ unsigned short As[64 * LDA];
  __shared__ unsigned short Wt[64 * LDA];
  __shared__ float red[2][4][64];
  int tid = threadIdx.x;
  int rowbase = blockIdx.x << 6;
  int b = rowbase >> 15;
  {
    const uint4* wsrc = (const uint4*)w0t;
    uint4* wdst = (uint4*)Wt;
    for (int i = tid; i < 832; i += 256) wdst[i] = wsrc[i];
  }
  {
    int rl = tid >> 2, part = tid & 3;
    int r = rowbase + rl;
    int n = ballidx[r];
    const uint4* psrc = (const uint4*)(pT + (((size_t)((b << 12) + n)) << 6));
    uint4* adst = (uint4*)(As + rl * LDA);
    adst[part * 2]     = psrc[part * 2];
    adst[part * 2 + 1] = psrc[part * 2 + 1];
    adst[8 + part] = make_uint4(0, 0, 0, 0);   // zero cols 64..95
    if (part == 0) {
      int ci = r >> 5;
      float4 c = centers4[ci];
      unsigned short* arow = As + rl * LDA;
      arow[64] = f2bf(__fsub_rn(xyz[(size_t)b * 12288 + n],        c.x));
      arow[65] = f2bf(__fsub_rn(xyz[(size_t)b * 12288 + 4096 + n], c.y));
      arow[66] = f2bf(__fsub_rn(xyz[(size_t)b * 12288 + 8192 + n], c.z));
    }
  }
  __syncthreads();
  int lane = tid & 63, w = tid >> 6;
  int mrow = (w << 4) + (lane & 15);
  int quad = lane >> 4;
  f32x4 acc[4];
#pragma unroll
  for (int nt = 0; nt < 4; ++nt) acc[nt] = (f32x4){0.f, 0.f, 0.f, 0.f};
#pragma unroll
  for (int kt = 0; kt < 3; ++kt) {
    int ko = kt * 32 + (quad << 3);
    bf16x8 a = *(const bf16x8*)(As + mrow * LDA + ko);
#pragma unroll
    for (int nt = 0; nt < 4; ++nt) {
      bf16x8 bb = *(const bf16x8*)(Wt + ((nt << 4) + (lane & 15)) * LDA + ko);
      acc[nt] = __builtin_amdgcn_mfma_f32_16x16x32_bf16(a, bb, acc[nt], 0, 0, 0);
    }
  }
#pragma unroll
  for (int nt = 0; nt < 4; ++nt) {
    int cch = (nt << 4) + (lane & 15);
    float bias = b0[cch];
    float ssum = 0.f, sq = 0.f;
#pragma unroll
    for (int r2 = 0; r2 < 4; ++r2) {
      float y = acc[nt][r2] + bias;
      int ml = (w << 4) + (quad << 2) + r2;
      feats1[(((size_t)(rowbase + ml)) << 6) + cch] = f2bf(y);
      ssum += y; sq += y * y;
    }
    ssum += __shfl_xor(ssum, 16); ssum += __shfl_xor(ssum, 32);
    sq   += __shfl_xor(sq, 16);   sq   += __shfl_xor(sq, 32);
    if (quad == 0) { red[0][w][cch] = ssum; red[1][w][cch] = sq; }
  }
  __syncthreads();
  if (tid < 64) {
    float a0 = red[0][0][tid] + red[0][1][tid] + red[0][2][tid] + red[0][3][tid];
    float a1 = red[1][0][tid] + red[1][1][tid] + red[1][2][tid] + red[1][3][tid];
    partials[(size_t)blockIdx.x * 256 + tid]      = a0;
    partials[(size_t)blockIdx.x * 256 + 64 + tid] = a1;
  }
}

// ---------------------------------------------------------------------------
// GEMM2: A = relu(scale*y1+shift) from feats1; K=64; out raw y2 + partials.
// ---------------------------------------------------------------------------
__global__ __launch_bounds__(256) void gemm2_kernel(
    const unsigned short* __restrict__ featsIn, const unsigned short* __restrict__ wt,
    const float* __restrict__ bias_g, const float* __restrict__ ss_in,
    unsigned short* __restrict__ featsOut, float* __restrict__ partials)
{
  __shared__ unsigned short As[64 * LDA];
  __shared__ unsigned short Wt[64 * LDA];
  __shared__ float red[2][4][64];
  __shared__ float ssl[128];
  int tid = threadIdx.x;
  int rowbase = blockIdx.x << 6;
  if (tid < 128) ssl[tid] = ss_in[tid];
  {
    const uint4* wsrc = (const uint4*)wt;
    uint4* wdst = (uint4*)Wt;
    for (int i = tid; i < 832; i += 256) wdst[i] = wsrc[i];
  }
  __syncthreads();
  {
    int rl = tid >> 2, part = tid & 3;
    size_t r = (size_t)rowbase + rl;
    union { uint4 v[2]; unsigned short u[16]; } t;
    const uint4* src = (const uint4*)(featsIn + (r << 6));
    t.v[0] = src[part * 2]; t.v[1] = src[part * 2 + 1];
    union { uint4 v[2]; unsigned short u[16]; } o;
#pragma unroll
    for (int e = 0; e < 16; ++e) {
      int cch = (part << 4) + e;
      float f = bf2f(t.u[e]);
      float y = fmaxf(f * ssl[cch] + ssl[64 + cch], 0.f);
      o.u[e] = f2bf(y);
    }
    uint4* adst = (uint4*)(As + rl * LDA + (part << 4));
    adst[0] = o.v[0]; adst[1] = o.v[1];
  }
  __syncthreads();
  int lane = tid & 63, w = tid >> 6;
  int mrow = (w << 4) + (lane & 15);
  int quad = lane >> 4;
  f32x4 acc[4];
#pragma unroll
  for (int nt = 0; nt < 4; ++nt) acc[nt] = (f32x4){0.f, 0.f, 0.f, 0.f};
#pragma unroll
  for (int kt = 0; kt < 2; ++kt) {
    int ko = kt * 32 + (quad << 3);
    bf16x8 a = *(const bf16x8*)(As + mrow * LDA + ko);
#pragma unroll
    for (int nt = 0; nt < 4; ++nt) {
      bf16x8 bb = *(const bf16x8*)(Wt + ((nt << 4) + (lane & 15)) * LDA + ko);
      acc[nt] = __builtin_amdgcn_mfma_f32_16x16x32_bf16(a, bb, acc[nt], 0, 0, 0);
    }
  }
#pragma unroll
  for (int nt = 0; nt < 4; ++nt) {
    int cch = (nt << 4) + (lane & 15);
    float bias = bias_g[cch];
    float ssum = 0.f, sq = 0.f;
#pragma unroll
    for (int r2 = 0; r2 < 4; ++r2) {
      float y = acc[nt][r2] + bias;
      int ml = (w << 4) + (quad << 2) + r2;
      featsOut[(((size_t)(rowbase + ml)) << 6) + cch] = f2bf(y);
      ssum += y; sq += y * y;
    }
    ssum += __shfl_xor(ssum, 16); ssum += __shfl_xor(ssum, 32);
    sq   += __shfl_xor(sq, 16);   sq   += __shfl_xor(sq, 32);
    if (quad == 0) { red[0][w][cch] = ssum; red[1][w][cch] = sq; }
  }
  __syncthreads();
  if (tid < 64) {
    float a0 = red[0][0][tid] + red[0][1][tid] + red[0][2][tid] + red[0][3][tid];
    float a1 = red[1][0][tid] + red[1][1][tid] + red[1][2][tid] + red[1][3][tid];
    partials[(size_t)blockIdx.x * 256 + tid]      = a0;
    partials[(size_t)blockIdx.x * 256 + 64 + tid] = a1;
  }
}

// ---------------------------------------------------------------------------
// GEMM3 stats pass: y3 = relu2(feats2)@W2 + b2 ; only channel partials, no store.
// ---------------------------------------------------------------------------
__global__ __launch_bounds__(256) void gemm3_stats_kernel(
    const unsigned short* __restrict__ feats2, const unsigned short* __restrict__ w2t,
    const float* __restrict__ b2, const float* __restrict__ ss2,
    float* __restrict__ partials)
{
  __shared__ unsigned short As[64 * LDA];
  __shared__ unsigned short Wt[128 * LDA];
  __shared__ float red[2][4][128];
  __shared__ float ssl[128];
  int tid = threadIdx.x;
  int rowbase = blockIdx.x << 6;
  if (tid < 128) ssl[tid] = ss2[tid];
  {
    const uint4* wsrc = (const uint4*)w2t;
    uint4* wdst = (uint4*)Wt;
    for (int i = tid; i < 1664; i += 256) wdst[i] = wsrc[i];
  }
  __syncthreads();
  {
    int rl = tid >> 2, part = tid & 3;
    size_t r = (size_t)rowbase + rl;
    union { uint4 v[2]; unsigned short u[16]; } t;
    const uint4* src = (const uint4*)(feats2 + (r << 6));
    t.v[0] = src[part * 2]; t.v[1] = src[part * 2 + 1];
    union { uint4 v[2]; unsigned short u[16]; } o;
#pragma unroll
    for (int e = 0; e < 16; ++e) {
      int cch = (part << 4) + e;
      float f = bf2f(t.u[e]);
      float y = fmaxf(f * ssl[cch] + ssl[64 + cch], 0.f);
      o.u[e] = f2bf(y);
    }
    uint4* adst = (uint4*)(As + rl * LDA + (part << 4));
    adst[0] = o.v[0]; adst[1] = o.v[1];
  }
  __syncthreads();
  int lane = tid & 63, w = tid >> 6;
  int mrow = (w << 4) + (lane & 15);
  int quad = lane >> 4;
  f32x4 acc[8];
#pragma unroll
  for (int nt = 0; nt < 8; ++nt) acc[nt] = (f32x4){0.f, 0.f, 0.f, 0.f};
#pragma unroll
  for (int kt = 0; kt < 2; ++kt) {
    int ko = kt * 32 + (quad << 3);
    bf16x8 a = *(const bf16x8*)(As + mrow * LDA + ko);
#pragma unroll
    for (int nt = 0; nt < 8; ++nt) {
      bf16x8 bb = *(const bf16x8*)(Wt + ((nt << 4) + (lane & 15)) * LDA + ko);
      acc[nt] = __builtin_amdgcn_mfma_f32_16x16x32_bf16(a, bb, acc[nt], 0, 0, 0);
    }
  }
#pragma unroll
  for (int nt = 0; nt < 8; ++nt) {
    int cch = (nt << 4) + (lane & 15);
    float bias = b2[cch];
    float ssum = 0.f, sq = 0.f;
#pragma unroll
    for (int r2 = 0; r2 < 4; ++r2) {
      float y = acc[nt][r2] + bias;
      ssum += y; sq += y * y;
    }
    ssum += __shfl_xor(ssum, 16); ssum += __shfl_xor(ssum, 32);
    sq   += __shfl_xor(sq, 16);   sq   += __shfl_xor(sq, 32);
    if (quad == 0) { red[0][w][cch] = ssum; red[1][w][cch] = sq; }
  }
  __syncthreads();
  if (tid < 128) {
    float a0 = red[0][0][tid] + red[0][1][tid] + red[0][2][tid] + red[0][3][tid];
    float a1 = red[1][0][tid] + red[1][1][tid] + red[1][2][tid] + red[1][3][tid];
    partials[(size_t)blockIdx.x * 256 + tid]       = a0;
    partials[(size_t)blockIdx.x * 256 + 128 + tid] = a1;
  }
}

// ---------------------------------------------------------------------------
// Final: recompute y3, apply BN3+relu, max over K=32, write [B,S,128] compact.
// ---------------------------------------------------------------------------
__global__ __launch_bounds__(256) void final_kernel(
    const unsigned short* __restrict__ feats2, const unsigned short* __restrict__ w2t,
    const float* __restrict__ b2, const float* __restrict__ ss2,
    const float* __restrict__ ss3, float* __restrict__ out_tmp)
{
  __shared__ unsigned short As[64 * LDA];
  __shared__ unsigned short Wt[128 * LDA];
  __shared__ float ssl[128];
  __shared__ unsigned mx[2][128];
  int tid = threadIdx.x;
  int rowbase = blockIdx.x << 6;
  if (tid < 128) ssl[tid] = ss2[tid];
  ((unsigned*)mx)[tid] = 0u;   // relu outputs >= 0, so 0 == -inf here
  {
    const uint4* wsrc = (const uint4*)w2t;
    uint4* wdst = (uint4*)Wt;
    for (int i = tid; i < 1664; i += 256) wdst[i] = wsrc[i];
  }
  __syncthreads();
  {
    int rl = tid >> 2, part = tid & 3;
    size_t r = (size_t)rowbase + rl;
    union { uint4 v[2]; unsigned short u[16]; } t;
    const uint4* src = (const uint4*)(feats2 + (r << 6));
    t.v[0] = src[part * 2]; t.v[1] = src[part * 2 + 1];
    union { uint4 v[2]; unsigned short u[16]; } o;
#pragma unroll
    for (int e = 0; e < 16; ++e) {
      int cch = (part << 4) + e;
      float f = bf2f(t.u[e]);
      float y = fmaxf(f * ssl[cch] + ssl[64 + cch], 0.f);
      o.u[e] = f2bf(y);
    }
    uint4* adst = (uint4*)(As + rl * LDA + (part << 4));
    adst[0] = o.v[0]; adst[1] = o.v[1];
  }
  __syncthreads();
  int lane = tid & 63, w = tid >> 6;
  int mrow = (w << 4) + (lane & 15);
  int quad = lane >> 4;
  f32x4 acc[8];
#pragma unroll
  for (int nt = 0; nt < 8; ++nt) acc[nt] = (f32x4){0.f, 0.f, 0.f, 0.f};
#pragma unroll
  for (int kt = 0; kt < 2; ++kt) {
    int ko = kt * 32 + (quad << 3);
    bf16x8 a = *(const bf16x8*)(As + mrow * LDA + ko);
#pragma unroll
    for (int nt = 0; nt < 8; ++nt) {
      bf16x8 bb = *(const bf16x8*)(Wt + ((nt << 4) + (lane & 15)) * LDA + ko);
      acc[nt] = __builtin_amdgcn_mfma_f32_16x16x32_bf16(a, bb, acc[nt], 0, 0, 0);
    }
  }
  int cloc = w >> 1;   // rows 0..31 -> center 0, rows 32..63 -> center 1
#pragma unroll
  for (int nt = 0; nt < 8; ++nt) {
    int cch = (nt << 4) + (lane & 15);
    float bias = b2[cch];
    float sc = ss3[cch], sh = ss3[128 + cch];
    float m = 0.f;
#pragma unroll
    for (int r2 = 0; r2 < 4; ++r2) {
      float y = acc[nt][r2] + bias;
      float tv = fmaxf(y * sc + sh, 0.f);
      m = fmaxf(m, tv);
    }
    atomicMax(&mx[cloc][cch], __float_as_uint(m));
  }
  __syncthreads();
  {
    int c2 = tid >> 7, cch = tid & 127;
    float v = __uint_as_float(mx[c2][cch]);
    int cg = (rowbase >> 5) + c2;            // global center index b*1024+s
    out_tmp[((size_t)cg << 7) + cch] = v;
  }
}

// ---------------------------------------------------------------------------
// stats reduce + finalize
// ---------------------------------------------------------------------------
__global__ __launch_bounds__(256) void reduce_kernel(const float* __restrict__ partials,
                                                     float* __restrict__ stats, int twoC)
{
  int tid = threadIdx.x;
  if (tid < twoC) {
    int row0 = blockIdx.x << 7;
    float s = 0.f;
    for (int r = 0; r < 128; ++r) s += partials[((size_t)(row0 + r)) * 256 + tid];
    atomicAdd(&stats[tid], s);
  }
}

__global__ void finalize_kernel(const float* __restrict__ stats, const float* __restrict__ g,
                                const float* __restrict__ be, float* __restrict__ ss, int C)
{
  int c = threadIdx.x;
  if (c < C) {
    const float invM = 1.f / 524288.f;
    float mean = stats[c] * invM;
    float ex2  = stats[C + c] * invM;
    float var  = ex2 - mean * mean;
    float sc   = g[c] / sqrtf(var + 1e-5f);
    ss[c]     = sc;
    ss[C + c] = be[c] - mean * sc;
  }
}

// ---------------------------------------------------------------------------
// out_tmp [B,S,128] -> d_out [B,128,S] (offset 49152)
// ---------------------------------------------------------------------------
__global__ __launch_bounds__(256) void transpose_out_kernel(const float* __restrict__ out_tmp,
                                                            float* __restrict__ out)
{
  __shared__ float t2[64][65];
  int tid = threadIdx.x;
  int b = blockIdx.x >> 5;
  int rest = blockIdx.x & 31;
  int s0 = (rest & 15) << 6;
  int c0 = (rest >> 4) << 6;
  for (int i = tid; i < 4096; i += 256) {
    int row = i >> 6, col = i & 63;
    t2[row][col] = out_tmp[((size_t)((b << 10) + s0 + row)) * 128 + c0 + col];
  }
  __syncthreads();
  for (int i = tid; i < 4096; i += 256) {
    int crow = i >> 6, scol = i & 63;
    out[49152 + ((size_t)b << 17) + (size_t)(c0 + crow) * 1024 + s0 + scol] = t2[scol][crow];
  }
}

// ---------------------------------------------------------------------------
extern "C" void kernel_launch(void* const* d_in, const int* in_sizes, int n_in,
                              void* d_out, int out_size, void* d_ws, size_t ws_size,
                              hipStream_t stream)
{
  (void)in_sizes; (void)n_in; (void)out_size; (void)ws_size;
  const float* xyz    = (const float*)d_in[0];
  const float* points = (const float*)d_in[1];
  const float* W0  = (const float*)d_in[2];
  const float* b0  = (const float*)d_in[3];
  const float* g0  = (const float*)d_in[4];
  const float* be0 = (const float*)d_in[5];
  const float* W1  = (const float*)d_in[6];
  const float* b1  = (const float*)d_in[7];
  const float* g1  = (const float*)d_in[8];
  const float* be1 = (const float*)d_in[9];
  const float* W2  = (const float*)d_in[10];
  const float* b2  = (const float*)d_in[11];
  const float* g2  = (const float*)d_in[12];
  const float* be2 = (const float*)d_in[13];
  float* out = (float*)d_out;

  char* base = (char*)d_ws;
  size_t off = 0;
  auto alloc = [&](size_t bytes) -> void* {
    void* p = base + off;
    off += (bytes + 255) & ~(size_t)255;
    return p;
  };
  unsigned short* pT     = (unsigned short*)alloc((size_t)16 * 4096 * 64 * 2);
  unsigned short* w0t    = (unsigned short*)alloc(64 * LDA * 2);
  unsigned short* w1t    = (unsigned short*)alloc(64 * LDA * 2);
  unsigned short* w2t    = (unsigned short*)alloc(128 * LDA * 2);
  float* stats_all       = (float*)alloc(512 * 4);
  float* ss_all          = (float*)alloc(512 * 4);
  float4* centers4       = (float4*)alloc((size_t)16 * 1024 * 16);
  int* ballidx           = (int*)alloc((size_t)16 * 1024 * 32 * 4);
  unsigned short* feats1 = (unsigned short*)alloc((size_t)524288 * 64 * 2);
  unsigned short* feats2 = (unsigned short*)alloc((size_t)524288 * 64 * 2);
  float* partials        = (float*)alloc((size_t)8192 * 256 * 4);
  float* out_tmp         = (float*)alloc((size_t)16 * 1024 * 128 * 4);

  float* stats1 = stats_all;       float* stats2 = stats_all + 128; float* stats3 = stats_all + 256;
  float* ss1 = ss_all;             float* ss2 = ss_all + 128;       float* ss3 = ss_all + 256;

  fps_prep_kernel<<<1041, 256, 0, stream>>>(xyz, points, W0, W1, W2, pT, w0t, w1t,
                                            w2t, stats_all, out, centers4);
  ball_kernel<<<64, 256, 0, stream>>>(xyz, centers4, ballidx);
  gemm1_kernel<<<8192, 256, 0, stream>>>(xyz, pT, w0t, b0, centers4, ballidx, feats1, partials);
  reduce_kernel<<<64, 256, 0, stream>>>(partials, stats1, 128);
  finalize_kernel<<<1, 64, 0, stream>>>(stats1, g0, be0, ss1, 64);
  gemm2_kernel<<<8192, 256, 0, stream>>>(feats1, w1t, b1, ss1, feats2, partials);
  reduce_kernel<<<64, 256, 0, stream>>>(partials, stats2, 128);
  finalize_kernel<<<1, 64, 0, stream>>>(stats2, g1, be1, ss2, 64);
  gemm3_stats_kernel<<<8192, 256, 0, stream>>>(feats2, w2t, b2, ss2, partials);
  reduce_kernel<<<64, 256, 0, stream>>>(partials, stats3, 256);
  finalize_kernel<<<1, 128, 0, stream>>>(stats3, g2, be2, ss3, 128);
  final_kernel<<<8192, 256, 0, stream>>>(feats2, w2t, b2, ss2, ss3, out_tmp);
  transpose_out_kernel<<<512, 256, 0, stream>>>(out_tmp, out);
}

// Round 6
// 1512.757 us; speedup vs baseline: 1.1707x; 1.1707x over previous
//
#include <hip/hip_runtime.h>
#include <hip/hip_bf16.h>
#include <cstdint>

// Problem constants
// B=16, N=4096, S=1024 (NPOINT), K=32 (NSAMPLE), CIN=64, MLP 67->64->64->128
// M = B*S*K = 524288 rows through the MLP.

typedef __attribute__((ext_vector_type(8))) short bf16x8;
typedef __attribute__((ext_vector_type(4))) float f32x4;

#define LDA 104   // bf16 LDS row stride: 208 B = 52 dwords -> 2-way (free) b128 bank pattern

__device__ __forceinline__ unsigned short f2bf(float f) {
  unsigned x = __float_as_uint(f);
  unsigned r = (x + 0x7FFFu + ((x >> 16) & 1u)) >> 16;  // RNE
  return (unsigned short)r;
}
__device__ __forceinline__ float bf2f(unsigned short u) {
  return __uint_as_float(((unsigned)u) << 16);
}

// DPP max-combine on a packed 64-bit key. DPP row ops are VALU-latency (~2-4cyc)
// vs ~120cyc for ds_permute-backed __shfl — this is the FPS critical path.
template <int CTRL>
__device__ __forceinline__ unsigned long long dppmax(unsigned long long k) {
  int lo = (int)(unsigned)k;
  int hi = (int)(unsigned)(k >> 32);
  int plo = __builtin_amdgcn_update_dpp(lo, lo, CTRL, 0xF, 0xF, false);
  int phi = __builtin_amdgcn_update_dpp(hi, hi, CTRL, 0xF, 0xF, false);
  unsigned long long o =
      ((unsigned long long)(unsigned)phi << 32) | (unsigned)plo;
  return (o > k) ? o : k;
}

// ---------------------------------------------------------------------------
// Fused FPS + prep, 256 threads/block. Blocks 0..15: FPS (one per batch).
// Blocks 16..1039: points transpose. Block 1040: weight tiles + stats zero.
//
// REGISTER-BUDGET NOTE (rounds 2-5 post-mortems): the FPS path needs
// px/py/pz/dist[16] = 64 floats + ~20 temps live across the loop. HIP
// __launch_bounds__(N,w)'s 2nd arg maps to amdgpu-waves-per-eu MINIMUM;
// the VGPR budget is set by the MAXIMUM waves/EU target, which launch_bounds
// cannot express — hence rounds 2-5 ALL partially spilled (VGPR_Count 36..68,
// always < ~84 needed). The direct knob is amdgpu_waves_per_eu(1,1): max=1
// waves/EU -> budget up to 512 VGPRs. Occupancy cost irrelevant here: only
// 16 FPS blocks exist and prep blocks are small, parallel, and transient.
//
// FPS per-iter serial chain: VALU dist-update -> DPP wave argmax (packed 64b
// key) -> lane63 writes key slot (double-buffered, contiguous) -> ONE barrier
// -> all threads read 4 keys (2x b128) + 3-step tree -> gi -> read center
// from LDS-staged xs/ys/zs. NO global stores in the loop (they force a
// vmcnt(0) drain at the barrier); centers buffered in LDS, written at end.
// Index selection bit-identical to numpy (max dist, tie -> min n, via
// key = bits(dist)<<32 | ~n).
// ---------------------------------------------------------------------------
__global__ __attribute__((amdgpu_flat_work_group_size(256, 256),
                          amdgpu_waves_per_eu(1, 1)))
void fps_prep_kernel(
    const float* __restrict__ xyz, const float* __restrict__ points,
    const float* __restrict__ W0, const float* __restrict__ W1,
    const float* __restrict__ W2, unsigned short* __restrict__ pT,
    unsigned short* __restrict__ w0t, unsigned short* __restrict__ w1t,
    unsigned short* __restrict__ w2t, float* __restrict__ stats_all,
    float* __restrict__ out, float4* __restrict__ centers4)
{
  __shared__ __align__(16) char smraw[61568];
  int tid = threadIdx.x;
  if (blockIdx.x >= 16) {
    int pb = blockIdx.x - 16;
    if (pb < 1024) {
      float (*tile)[65] = (float (*)[65])smraw;
      int b = pb >> 6;
      int n0 = (pb & 63) << 6;
      const float* pbp = points + ((size_t)b << 18);
      for (int i = tid; i < 4096; i += 256) {
        int cc = i >> 6, nn = i & 63;
        tile[cc][nn] = pbp[((size_t)cc << 12) + n0 + nn];
      }
      __syncthreads();
      for (int i = tid; i < 4096; i += 256) {
        int nn = i >> 6, cc = i & 63;
        pT[(((size_t)((b << 12) + n0 + nn)) << 6) + cc] = f2bf(tile[cc][nn]);
      }
    } else {
      // w0t: 64x104, w1t: 64x104, w2t: 128x104, stats: 512 floats
      for (int i = tid; i < 27136; i += 256) {
        if (i < 6656) {
          int nn = i / 104, kk = i % 104;
          float v = (kk < 64) ? W0[(3 + kk) * 64 + nn]
                              : ((kk < 67) ? W0[(kk - 64) * 64 + nn] : 0.f);
          w0t[i] = f2bf(v);
        } else if (i < 13312) {
          int j = i - 6656; int nn = j / 104, kk = j % 104;
          float v = (kk < 64) ? W1[kk * 64 + nn] : 0.f;
          w1t[j] = f2bf(v);
        } else if (i < 26624) {
          int j = i - 13312; int nn = j / 104, kk = j % 104;
          float v = (kk < 64) ? W2[kk * 128 + nn] : 0.f;
          w2t[j] = f2bf(v);
        } else {
          stats_all[i - 26624] = 0.f;
        }
      }
    }
    return;
  }
  // ---- FPS path ----
  float* xs  = (float*)smraw;                 // [4096]
  float* ys  = xs + 4096;                     // [4096]
  float* zs  = ys + 4096;                     // [4096]  (ends 49152 B)
  float* cxl = zs + 4096;                     // [1024]
  float* cyl = cxl + 1024;                    // [1024]
  float* czl = cyl + 1024;                    // [1024]  (ends 61440 B)
  unsigned long long (*keybuf)[4] =
      (unsigned long long (*)[4])(smraw + 61440);  // [2][4], 16B-aligned

  int b = blockIdx.x;
  const float* xb = xyz + (size_t)b * 12288;
  float px[16], py[16], pz[16], dist[16];
#pragma unroll
  for (int j = 0; j < 16; ++j) {
    int n = tid + (j << 8);
    px[j] = xb[n]; py[j] = xb[4096 + n]; pz[j] = xb[8192 + n];
    xs[n] = px[j]; ys[n] = py[j]; zs[n] = pz[j];
    dist[j] = 1e10f;
  }
  __syncthreads();
  float cx = xs[0], cy = ys[0], cz = zs[0];
  if (tid == 0) { cxl[0] = cx; cyl[0] = cy; czl[0] = cz; }
  int w = tid >> 6;
  int lane = tid & 63;
  for (int it = 1; it < 1024; ++it) {
    float bv = -1.f; int bi = 0;
#pragma unroll
    for (int j = 0; j < 16; ++j) {
      float dx = __fsub_rn(px[j], cx);
      float dy = __fsub_rn(py[j], cy);
      float dz = __fsub_rn(pz[j], cz);
      float d  = __fadd_rn(__fadd_rn(__fmul_rn(dx, dx), __fmul_rn(dy, dy)),
                           __fmul_rn(dz, dz));
      float nd = fminf(dist[j], d);
      dist[j] = nd;
      if (nd > bv) { bv = nd; bi = tid + (j << 8); }  // strict >, j asc => min n
    }
    // pack: high 32 = dist bits (nonneg float => monotone), low 32 = ~n
    unsigned long long k =
        ((unsigned long long)__float_as_uint(bv) << 32) | (unsigned)(~bi);
    k = dppmax<0xB1>(k);    // quad_perm [1,0,3,2]  : xor 1
    k = dppmax<0x4E>(k);    // quad_perm [2,3,0,1]  : xor 2
    k = dppmax<0x141>(k);   // row_half_mirror      : xor 4
    k = dppmax<0x140>(k);   // row_mirror           : xor 8
    k = dppmax<0x142>(k);   // row_bcast15          : rows 0->1, 2->3
    k = dppmax<0x143>(k);   // row_bcast31          : rows 01 -> 23
    int p = it & 1;
    if (lane == 63) keybuf[p][w] = k;   // lane63 holds the wave max
    __syncthreads();
    // combine 4 wave keys: 2x b128 reads + 3-compare tree (uniform)
    uint4 ka2 = *(const uint4*)&keybuf[p][0];
    uint4 kb2 = *(const uint4*)&keybuf[p][2];
    unsigned long long k0 = ((unsigned long long)ka2.y << 32) | ka2.x;
    unsigned long long k1 = ((unsigned long long)ka2.w << 32) | ka2.z;
    unsigned long long k2 = ((unsigned long long)kb2.y << 32) | kb2.x;
    unsigned long long k3 = ((unsigned long long)kb2.w << 32) | kb2.z;
    unsigned long long m01 = (k1 > k0) ? k1 : k0;
    unsigned long long m23 = (k3 > k2) ? k3 : k2;
    unsigned long long km  = (m23 > m01) ? m23 : m01;
    int gi = (int)(~(unsigned)km) & 4095;
    cx = xs[gi]; cy = ys[gi]; cz = zs[gi];
    if (tid == 0) { cxl[it] = cx; cyl[it] = cy; czl[it] = cz; }
    // no second barrier: next iter writes keybuf[(it+1)&1], disjoint slot;
    // a wave re-writes this slot only after passing the NEXT barrier, which
    // orders it after every wave's read above.
  }
  __syncthreads();
  for (int it = tid; it < 1024; it += 256) {
    float x = cxl[it], y = cyl[it], z = czl[it];
    out[b * 3072 + it]        = x;
    out[b * 3072 + 1024 + it] = y;
    out[b * 3072 + 2048 + it] = z;
    centers4[(b << 10) + it]  = make_float4(x, y, z, 0.f);
  }
}

// ---------------------------------------------------------------------------
// Ball query: thread = center; scan n ascending, first <=32 hits, early exit.
// ---------------------------------------------------------------------------
__global__ __launch_bounds__(256) void ball_kernel(const float* __restrict__ xyz,
                                                   const float4* __restrict__ centers4,
                                                   int* __restrict__ ballidx)
{
  __shared__ float xs[4096], ys[4096], zs[4096];
  int b = blockIdx.x >> 2, tid = threadIdx.x;
  int s = ((blockIdx.x & 3) << 8) + tid;
  const float* xb = xyz + (size_t)b * 12288;
  for (int i = tid; i < 4096; i += 256) {
    xs[i] = xb[i]; ys[i] = xb[4096 + i]; zs[i] = xb[8192 + i];
  }
  __syncthreads();
  float4 c = centers4[(b << 10) + s];
  int* ob = ballidx + (((size_t)((b << 10) + s)) << 5);
  int cnt = 0, first = 0;
  for (int n = 0; n < 4096; ++n) {
    if (cnt < 32) {
      float dx = __fsub_rn(xs[n], c.x);
      float dy = __fsub_rn(ys[n], c.y);
      float dz = __fsub_rn(zs[n], c.z);
      float d  = __fadd_rn(__fadd_rn(__fmul_rn(dx, dx), __fmul_rn(dy, dy)),
                           __fmul_rn(dz, dz));
      if (!(d > 0.04f)) {        // 0.04f == f32(RADIUS**2), matches ref compare
        if (cnt == 0) first = n;
        ob[cnt] = n; ++cnt;
      }
    }
    if (__all(cnt >= 32)) break;
  }
  for (int k = cnt; k < 32; ++k) ob[k] = first;
}

// ---------------------------------------------------------------------------
// GEMM1: gather (pT rows + g_xyz) -> A[64 x 96(pad104)] bf16, W'T0, MFMA,
// write raw y1 bf16 [M,64] + per-block channel partials (sum, sumsq).
// ---------------------------------------------------------------------------
__global__ __launch_bounds__(256) void gemm1_kernel(
    const float* __restrict__ xyz, const unsigned short* __restrict__ pT,
    const unsigned short* __restrict__ w0t, const float* __restrict__ b0,
    const float4* __restrict__ centers4, const int* __restrict__ ballidx,
    unsigned short* __restrict__ feats1, float* __restrict__ partials)
{
  __shared__ unsigned short As[64 * LDA];
  __shared__ unsigned short Wt[64 * LDA];
  __shared__ float red[2][4][64];
  int tid = threadIdx.x;
  int rowbase = blockIdx.x << 6;
  int b = rowbase >> 15;
  {
    const uint4* wsrc = (const uint4*)w0t;
    uint4* wdst = (uint4*)Wt;
    for (int i = tid; i < 832; i += 256) wdst[i] = wsrc[i];
  }
  {
    int rl = tid >> 2, part = tid & 3;
    int r = rowbase + rl;
    int n = ballidx[r];
    const uint4* psrc = (const uint4*)(pT + (((size_t)((b << 12) + n)) << 6));
    uint4* adst = (uint4*)(As + rl * LDA);
    adst[part * 2]     = psrc[part * 2];
    adst[part * 2 + 1] = psrc[part * 2 + 1];
    adst[8 + part] = make_uint4(0, 0, 0, 0);   // zero cols 64..95
    if (part == 0) {
      int ci = r >> 5;
      float4 c = centers4[ci];
      unsigned short* arow = As + rl * LDA;
      arow[64] = f2bf(__fsub_rn(xyz[(size_t)b * 12288 + n],        c.x));
      arow[65] = f2bf(__fsub_rn(xyz[(size_t)b * 12288 + 4096 + n], c.y));
      arow[66] = f2bf(__fsub_rn(xyz[(size_t)b * 12288 + 8192 + n], c.z));
    }
  }
  __syncthreads();
  int lane = tid & 63, w = tid >> 6;
  int mrow = (w << 4) + (lane & 15);
  int quad = lane >> 4;
  f32x4 acc[4];
#pragma unroll
  for (int nt = 0; nt < 4; ++nt) acc[nt] = (f32x4){0.f, 0.f, 0.f, 0.f};
#pragma unroll
  for (int kt = 0; kt < 3; ++kt) {
    int ko = kt * 32 + (quad << 3);
    bf16x8 a = *(const bf16x8*)(As + mrow * LDA + ko);
#pragma unroll
    for (int nt = 0; nt < 4; ++nt) {
      bf16x8 bb = *(const bf16x8*)(Wt + ((nt << 4) + (lane & 15)) * LDA + ko);
      acc[nt] = __builtin_amdgcn_mfma_f32_16x16x32_bf16(a, bb, acc[nt], 0, 0, 0);
    }
  }
#pragma unroll
  for (int nt = 0; nt < 4; ++nt) {
    int cch = (nt << 4) + (lane & 15);
    float bias = b0[cch];
    float ssum = 0.f, sq = 0.f;
#pragma unroll
    for (int r2 = 0; r2 < 4; ++r2) {
      float y = acc[nt][r2] + bias;
      int ml = (w << 4) + (quad << 2) + r2;
      feats1[(((size_t)(rowbase + ml)) << 6) + cch] = f2bf(y);
      ssum += y; sq += y * y;
    }
    ssum += __shfl_xor(ssum, 16); ssum += __shfl_xor(ssum, 32);
    sq   += __shfl_xor(sq, 16);   sq   += __shfl_xor(sq, 32);
    if (quad == 0) { red[0][w][cch] = ssum; red[1][w][cch] = sq; }
  }
  __syncthreads();
  if (tid < 64) {
    float a0 = red[0][0][tid] + red[0][1][tid] + red[0][2][tid] + red[0][3][tid];
    float a1 = red[1][0][tid] + red[1][1][tid] + red[1][2][tid] + red[1][3][tid];
    partials[(size_t)blockIdx.x * 256 + tid]      = a0;
    partials[(size_t)blockIdx.x * 256 + 64 + tid] = a1;
  }
}

// ---------------------------------------------------------------------------
// GEMM2: A = relu(scale*y1+shift) from feats1; K=64; out raw y2 + partials.
// ---------------------------------------------------------------------------
__global__ __launch_bounds__(256) void gemm2_kernel(
    const unsigned short* __restrict__ featsIn, const unsigned short* __restrict__ wt,
    const float* __restrict__ bias_g, const float* __restrict__ ss_in,
    unsigned short* __restrict__ featsOut, float* __restrict__ partials)
{
  __shared__ unsigned short As[64 * LDA];
  __shared__ unsigned short Wt[64 * LDA];
  __shared__ float red[2][4][64];
  __shared__ float ssl[128];
  int tid = threadIdx.x;
  int rowbase = blockIdx.x << 6;
  if (tid < 128) ssl[tid] = ss_in[tid];
  {
    const uint4* wsrc = (const uint4*)wt;
    uint4* wdst = (uint4*)Wt;
    for (int i = tid; i < 832; i += 256) wdst[i] = wsrc[i];
  }
  __syncthreads();
  {
    int rl = tid >> 2, part = tid & 3;
    size_t r = (size_t)rowbase + rl;
    union { uint4 v[2]; unsigned short u[16]; } t;
    const uint4* src = (const uint4*)(featsIn + (r << 6));
    t.v[0] = src[part * 2]; t.v[1] = src[part * 2 + 1];
    union { uint4 v[2]; unsigned short u[16]; } o;
#pragma unroll
    for (int e = 0; e < 16; ++e) {
      int cch = (part << 4) + e;
      float f = bf2f(t.u[e]);
      float y = fmaxf(f * ssl[cch] + ssl[64 + cch], 0.f);
      o.u[e] = f2bf(y);
    }
    uint4* adst = (uint4*)(As + rl * LDA + (part << 4));
    adst[0] = o.v[0]; adst[1] = o.v[1];
  }
  __syncthreads();
  int lane = tid & 63, w = tid >> 6;
  int mrow = (w << 4) + (lane & 15);
  int quad = lane >> 4;
  f32x4 acc[4];
#pragma unroll
  for (int nt = 0; nt < 4; ++nt) acc[nt] = (f32x4){0.f, 0.f, 0.f, 0.f};
#pragma unroll
  for (int kt = 0; kt < 2; ++kt) {
    int ko = kt * 32 + (quad << 3);
    bf16x8 a = *(const bf16x8*)(As + mrow * LDA + ko);
#pragma unroll
    for (int nt = 0; nt < 4; ++nt) {
      bf16x8 bb = *(const bf16x8*)(Wt + ((nt << 4) + (lane & 15)) * LDA + ko);
      acc[nt] = __builtin_amdgcn_mfma_f32_16x16x32_bf16(a, bb, acc[nt], 0, 0, 0);
    }
  }
#pragma unroll
  for (int nt = 0; nt < 4; ++nt) {
    int cch = (nt << 4) + (lane & 15);
    float bias = bias_g[cch];
    float ssum = 0.f, sq = 0.f;
#pragma unroll
    for (int r2 = 0; r2 < 4; ++r2) {
      float y = acc[nt][r2] + bias;
      int ml = (w << 4) + (quad << 2) + r2;
      featsOut[(((size_t)(rowbase + ml)) << 6) + cch] = f2bf(y);
      ssum += y; sq += y * y;
    }
    ssum += __shfl_xor(ssum, 16); ssum += __shfl_xor(ssum, 32);
    sq   += __shfl_xor(sq, 16);   sq   += __shfl_xor(sq, 32);
    if (quad == 0) { red[0][w][cch] = ssum; red[1][w][cch] = sq; }
  }
  __syncthreads();
  if (tid < 64) {
    float a0 = red[0][0][tid] + red[0][1][tid] + red[0][2][tid] + red[0][3][tid];
    float a1 = red[1][0][tid] + red[1][1][tid] + red[1][2][tid] + red[1][3][tid];
    partials[(size_t)blockIdx.x * 256 + tid]      = a0;
    partials[(size_t)blockIdx.x * 256 + 64 + tid] = a1;
  }
}

// ---------------------------------------------------------------------------
// GEMM3 stats pass: y3 = relu2(feats2)@W2 + b2 ; only channel partials, no store.
// ---------------------------------------------------------------------------
__global__ __launch_bounds__(256) void gemm3_stats_kernel(
    const unsigned short* __restrict__ feats2, const unsigned short* __restrict__ w2t,
    const float* __restrict__ b2, const float* __restrict__ ss2,
    float* __restrict__ partials)
{
  __shared__ unsigned short As[64 * LDA];
  __shared__ unsigned short Wt[128 * LDA];
  __shared__ float red[2][4][128];
  __shared__ float ssl[128];
  int tid = threadIdx.x;
  int rowbase = blockIdx.x << 6;
  if (tid < 128) ssl[tid] = ss2[tid];
  {
    const uint4* wsrc = (const uint4*)w2t;
    uint4* wdst = (uint4*)Wt;
    for (int i = tid; i < 1664; i += 256) wdst[i] = wsrc[i];
  }
  __syncthreads();
  {
    int rl = tid >> 2, part = tid & 3;
    size_t r = (size_t)rowbase + rl;
    union { uint4 v[2]; unsigned short u[16]; } t;
    const uint4* src = (const uint4*)(feats2 + (r << 6));
    t.v[0] = src[part * 2]; t.v[1] = src[part * 2 + 1];
    union { uint4 v[2]; unsigned short u[16]; } o;
#pragma unroll
    for (int e = 0; e < 16; ++e) {
      int cch = (part << 4) + e;
      float f = bf2f(t.u[e]);
      float y = fmaxf(f * ssl[cch] + ssl[64 + cch], 0.f);
      o.u[e] = f2bf(y);
    }
    uint4* adst = (uint4*)(As + rl * LDA + (part << 4));
    adst[0] = o.v[0]; adst[1] = o.v[1];
  }
  __syncthreads();
  int lane = tid & 63, w = tid >> 6;
  int mrow = (w << 4) + (lane & 15);
  int quad = lane >> 4;
  f32x4 acc[8];
#pragma unroll
  for (int nt = 0; nt < 8; ++nt) acc[nt] = (f32x4){0.f, 0.f, 0.f, 0.f};
#pragma unroll
  for (int kt = 0; kt < 2; ++kt) {
    int ko = kt * 32 + (quad << 3);
    bf16x8 a = *(const bf16x8*)(As + mrow * LDA + ko);
#pragma unroll
    for (int nt = 0; nt < 8; ++nt) {
      bf16x8 bb = *(const bf16x8*)(Wt + ((nt << 4) + (lane & 15)) * LDA + ko);
      acc[nt] = __builtin_amdgcn_mfma_f32_16x16x32_bf16(a, bb, acc[nt], 0, 0, 0);
    }
  }
#pragma unroll
  for (int nt = 0; nt < 8; ++nt) {
    int cch = (nt << 4) + (lane & 15);
    float bias = b2[cch];
    float ssum = 0.f, sq = 0.f;
#pragma unroll
    for (int r2 = 0; r2 < 4; ++r2) {
      float y = acc[nt][r2] + bias;
      ssum += y; sq += y * y;
    }
    ssum += __shfl_xor(ssum, 16); ssum += __shfl_xor(ssum, 32);
    sq   += __shfl_xor(sq, 16);   sq   += __shfl_xor(sq, 32);
    if (quad == 0) { red[0][w][cch] = ssum; red[1][w][cch] = sq; }
  }
  __syncthreads();
  if (tid < 128) {
    float a0 = red[0][0][tid] + red[0][1][tid] + red[0][2][tid] + red[0][3][tid];
    float a1 = red[1][0][tid] + red[1][1][tid] + red[1][2][tid] + red[1][3][tid];
    partials[(size_t)blockIdx.x * 256 + tid]       = a0;
    partials[(size_t)blockIdx.x * 256 + 128 + tid] = a1;
  }
}

// ---------------------------------------------------------------------------
// Final: recompute y3, apply BN3+relu, max over K=32, write [B,S,128] compact.
// ---------------------------------------------------------------------------
__global__ __launch_bounds__(256) void final_kernel(
    const unsigned short* __restrict__ feats2, const unsigned short* __restrict__ w2t,
    const float* __restrict__ b2, const float* __restrict__ ss2,
    const float* __restrict__ ss3, float* __restrict__ out_tmp)
{
  __shared__ unsigned short As[64 * LDA];
  __shared__ unsigned short Wt[128 * LDA];
  __shared__ float ssl[128];
  __shared__ unsigned mx[2][128];
  int tid = threadIdx.x;
  int rowbase = blockIdx.x << 6;
  if (tid < 128) ssl[tid] = ss2[tid];
  ((unsigned*)mx)[tid] = 0u;   // relu outputs >= 0, so 0 == -inf here
  {
    const uint4* wsrc = (const uint4*)w2t;
    uint4* wdst = (uint4*)Wt;
    for (int i = tid; i < 1664; i += 256) wdst[i] = wsrc[i];
  }
  __syncthreads();
  {
    int rl = tid >> 2, part = tid & 3;
    size_t r = (size_t)rowbase + rl;
    union { uint4 v[2]; unsigned short u[16]; } t;
    const uint4* src = (const uint4*)(feats2 + (r << 6));
    t.v[0] = src[part * 2]; t.v[1] = src[part * 2 + 1];
    union { uint4 v[2]; unsigned short u[16]; } o;
#pragma unroll
    for (int e = 0; e < 16; ++e) {
      int cch = (part << 4) + e;
      float f = bf2f(t.u[e]);
      float y = fmaxf(f * ssl[cch] + ssl[64 + cch], 0.f);
      o.u[e] = f2bf(y);
    }
    uint4* adst = (uint4*)(As + rl * LDA + (part << 4));
    adst[0] = o.v[0]; adst[1] = o.v[1];
  }
  __syncthreads();
  int lane = tid & 63, w = tid >> 6;
  int mrow = (w << 4) + (lane & 15);
  int quad = lane >> 4;
  f32x4 acc[8];
#pragma unroll
  for (int nt = 0; nt < 8; ++nt) acc[nt] = (f32x4){0.f, 0.f, 0.f, 0.f};
#pragma unroll
  for (int kt = 0; kt < 2; ++kt) {
    int ko = kt * 32 + (quad << 3);
    bf16x8 a = *(const bf16x8*)(As + mrow * LDA + ko);
#pragma unroll
    for (int nt = 0; nt < 8; ++nt) {
      bf16x8 bb = *(const bf16x8*)(Wt + ((nt << 4) + (lane & 15)) * LDA + ko);
      acc[nt] = __builtin_amdgcn_mfma_f32_16x16x32_bf16(a, bb, acc[nt], 0, 0, 0);
    }
  }
  int cloc = w >> 1;   // rows 0..31 -> center 0, rows 32..63 -> center 1
#pragma unroll
  for (int nt = 0; nt < 8; ++nt) {
    int cch = (nt << 4) + (lane & 15);
    float bias = b2[cch];
    float sc = ss3[cch], sh = ss3[128 + cch];
    float m = 0.f;
#pragma unroll
    for (int r2 = 0; r2 < 4; ++r2) {
      float y = acc[nt][r2] + bias;
      float tv = fmaxf(y * sc + sh, 0.f);
      m = fmaxf(m, tv);
    }
    atomicMax(&mx[cloc][cch], __float_as_uint(m));
  }
  __syncthreads();
  {
    int c2 = tid >> 7, cch = tid & 127;
    float v = __uint_as_float(mx[c2][cch]);
    int cg = (rowbase >> 5) + c2;            // global center index b*1024+s
    out_tmp[((size_t)cg << 7) + cch] = v;
  }
}

// ---------------------------------------------------------------------------
// stats reduce + finalize
// ---------------------------------------------------------------------------
__global__ __launch_bounds__(256) void reduce_kernel(const float* __restrict__ partials,
                                                     float* __restrict__ stats, int twoC)
{
  int tid = threadIdx.x;
  if (tid < twoC) {
    int row0 = blockIdx.x << 7;
    float s = 0.f;
    for (int r = 0; r < 128; ++r) s += partials[((size_t)(row0 + r)) * 256 + tid];
    atomicAdd(&stats[tid], s);
  }
}

__global__ void finalize_kernel(const float* __restrict__ stats, const float* __restrict__ g,
                                const float* __restrict__ be, float* __restrict__ ss, int C)
{
  int c = threadIdx.x;
  if (c < C) {
    const float invM = 1.f / 524288.f;
    float mean = stats[c] * invM;
    float ex2  = stats[C + c] * invM;
    float var  = ex2 - mean * mean;
    float sc   = g[c] / sqrtf(var + 1e-5f);
    ss[c]     = sc;
    ss[C + c] = be[c] - mean * sc;
  }
}

// ---------------------------------------------------------------------------
// out_tmp [B,S,128] -> d_out [B,128,S] (offset 49152)
// ---------------------------------------------------------------------------
__global__ __launch_bounds__(256) void transpose_out_kernel(const float* __restrict__ out_tmp,
                                                            float* __restrict__ out)
{
  __shared__ float t2[64][65];
  int tid = threadIdx.x;
  int b = blockIdx.x >> 5;
  int rest = blockIdx.x & 31;
  int s0 = (rest & 15) << 6;
  int c0 = (rest >> 4) << 6;
  for (int i = tid; i < 4096; i += 256) {
    int row = i >> 6, col = i & 63;
    t2[row][col] = out_tmp[((size_t)((b << 10) + s0 + row)) * 128 + c0 + col];
  }
  __syncthreads();
  for (int i = tid; i < 4096; i += 256) {
    int crow = i >> 6, scol = i & 63;
    out[49152 + ((size_t)b << 17) + (size_t)(c0 + crow) * 1024 + s0 + scol] = t2[scol][crow];
  }
}

// ---------------------------------------------------------------------------
extern "C" void kernel_launch(void* const* d_in, const int* in_sizes, int n_in,
                              void* d_out, int out_size, void* d_ws, size_t ws_size,
                              hipStream_t stream)
{
  (void)in_sizes; (void)n_in; (void)out_size; (void)ws_size;
  const float* xyz    = (const float*)d_in[0];
  const float* points = (const float*)d_in[1];
  const float* W0  = (const float*)d_in[2];
  const float* b0  = (const float*)d_in[3];
  const float* g0  = (const float*)d_in[4];
  const float* be0 = (const float*)d_in[5];
  const float* W1  = (const float*)d_in[6];
  const float* b1  = (const float*)d_in[7];
  const float* g1  = (const float*)d_in[8];
  const float* be1 = (const float*)d_in[9];
  const float* W2  = (const float*)d_in[10];
  const float* b2  = (const float*)d_in[11];
  const float* g2  = (const float*)d_in[12];
  const float* be2 = (const float*)d_in[13];
  float* out = (float*)d_out;

  char* base = (char*)d_ws;
  size_t off = 0;
  auto alloc = [&](size_t bytes) -> void* {
    void* p = base + off;
    off += (bytes + 255) & ~(size_t)255;
    return p;
  };
  unsigned short* pT     = (unsigned short*)alloc((size_t)16 * 4096 * 64 * 2);
  unsigned short* w0t    = (unsigned short*)alloc(64 * LDA * 2);
  unsigned short* w1t    = (unsigned short*)alloc(64 * LDA * 2);
  unsigned short* w2t    = (unsigned short*)alloc(128 * LDA * 2);
  float* stats_all       = (float*)alloc(512 * 4);
  float* ss_all          = (float*)alloc(512 * 4);
  float4* centers4       = (float4*)alloc((size_t)16 * 1024 * 16);
  int* ballidx           = (int*)alloc((size_t)16 * 1024 * 32 * 4);
  unsigned short* feats1 = (unsigned short*)alloc((size_t)524288 * 64 * 2);
  unsigned short* feats2 = (unsigned short*)alloc((size_t)524288 * 64 * 2);
  float* partials        = (float*)alloc((size_t)8192 * 256 * 4);
  float* out_tmp         = (float*)alloc((size_t)16 * 1024 * 128 * 4);

  float* stats1 = stats_all;       float* stats2 = stats_all + 128; float* stats3 = stats_all + 256;
  float* ss1 = ss_all;             float* ss2 = ss_all + 128;       float* ss3 = ss_all + 256;

  fps_prep_kernel<<<1041, 256, 0, stream>>>(xyz, points, W0, W1, W2, pT, w0t, w1t,
                                            w2t, stats_all, out, centers4);
  ball_kernel<<<64, 256, 0, stream>>>(xyz, centers4, ballidx);
  gemm1_kernel<<<8192, 256, 0, stream>>>(xyz, pT, w0t, b0, centers4, ballidx, feats1, partials);
  reduce_kernel<<<64, 256, 0, stream>>>(partials, stats1, 128);
  finalize_kernel<<<1, 64, 0, stream>>>(stats1, g0, be0, ss1, 64);
  gemm2_kernel<<<8192, 256, 0, stream>>>(feats1, w1t, b1, ss1, feats2, partials);
  reduce_kernel<<<64, 256, 0, stream>>>(partials, stats2, 128);
  finalize_kernel<<<1, 64, 0, stream>>>(stats2, g1, be1, ss2, 64);
  gemm3_stats_kernel<<<8192, 256, 0, stream>>>(feats2, w2t, b2, ss2, partials);
  reduce_kernel<<<64, 256, 0, stream>>>(partials, stats3, 256);
  finalize_kernel<<<1, 128, 0, stream>>>(stats3, g2, be2, ss3, 128);
  final_kernel<<<8192, 256, 0, stream>>>(feats2, w2t, b2, ss2, ss3, out_tmp);
  transpose_out_kernel<<<512, 256, 0, stream>>>(out_tmp, out);
}

// Round 7
// 967.824 us; speedup vs baseline: 1.8298x; 1.5630x over previous
//
#include <hip/hip_runtime.h>
#include <hip/hip_bf16.h>
#include <cstdint>

// Problem constants
// B=16, N=4096, S=1024 (NPOINT), K=32 (NSAMPLE), CIN=64, MLP 67->64->64->128
// M = B*S*K = 524288 rows through the MLP.

typedef __attribute__((ext_vector_type(8))) short bf16x8;
typedef __attribute__((ext_vector_type(4))) float f32x4;

#define LDA 104   // bf16 LDS row stride: 208 B = 52 dwords -> 2-way (free) b128 bank pattern

__device__ __forceinline__ unsigned short f2bf(float f) {
  unsigned x = __float_as_uint(f);
  unsigned r = (x + 0x7FFFu + ((x >> 16) & 1u)) >> 16;  // RNE
  return (unsigned short)r;
}
__device__ __forceinline__ float bf2f(unsigned short u) {
  return __uint_as_float(((unsigned)u) << 16);
}

// DPP max-combine on a packed 64-bit key. DPP row ops are VALU-latency (~2-4cyc)
// vs ~120cyc for ds_permute-backed __shfl — this is the FPS critical path.
template <int CTRL>
__device__ __forceinline__ unsigned long long dppmax(unsigned long long k) {
  int lo = (int)(unsigned)k;
  int hi = (int)(unsigned)(k >> 32);
  int plo = __builtin_amdgcn_update_dpp(lo, lo, CTRL, 0xF, 0xF, false);
  int phi = __builtin_amdgcn_update_dpp(hi, hi, CTRL, 0xF, 0xF, false);
  unsigned long long o =
      ((unsigned long long)(unsigned)phi << 32) | (unsigned)plo;
  return (o > k) ? o : k;
}

// ---------------------------------------------------------------------------
// Fused FPS + prep, 256 threads/block. Blocks 0..15: FPS (one per batch).
// Blocks 16..1039: points transpose. Block 1040: weight tiles + stats zero.
//
// REGISTER-BUDGET NOTE (rounds 2-5 post-mortems): the FPS path needs
// px/py/pz/dist[16] = 64 floats + ~20 temps live across the loop. HIP
// __launch_bounds__(N,w)'s 2nd arg maps to amdgpu-waves-per-eu MINIMUM;
// the VGPR budget is set by the MAXIMUM waves/EU target, which launch_bounds
// cannot express — hence rounds 2-5 ALL partially spilled (VGPR_Count 36..68,
// always < ~84 needed). The direct knob is amdgpu_waves_per_eu(1,1): max=1
// waves/EU -> budget up to 512 VGPRs. Round 6: fps dropped out of the top-5
// (878 -> <630 us) with this attribute — keep it.
//
// FPS per-iter serial chain: VALU dist-update -> DPP wave argmax (packed 64b
// key) -> lane63 writes key slot (double-buffered, contiguous) -> ONE barrier
// -> all threads read 4 keys (2x b128) + 3-step tree -> gi -> read center
// from LDS-staged xs/ys/zs. NO global stores in the loop (they force a
// vmcnt(0) drain at the barrier); centers buffered in LDS, written at end.
// Index selection bit-identical to numpy (max dist, tie -> min n, via
// key = bits(dist)<<32 | ~n).
// ---------------------------------------------------------------------------
__global__ __attribute__((amdgpu_flat_work_group_size(256, 256),
                          amdgpu_waves_per_eu(1, 1)))
void fps_prep_kernel(
    const float* __restrict__ xyz, const float* __restrict__ points,
    const float* __restrict__ W0, const float* __restrict__ W1,
    const float* __restrict__ W2, unsigned short* __restrict__ pT,
    unsigned short* __restrict__ w0t, unsigned short* __restrict__ w1t,
    unsigned short* __restrict__ w2t, float* __restrict__ stats_all,
    float* __restrict__ out, float4* __restrict__ centers4)
{
  __shared__ __align__(16) char smraw[61568];
  int tid = threadIdx.x;
  if (blockIdx.x >= 16) {
    int pb = blockIdx.x - 16;
    if (pb < 1024) {
      float (*tile)[65] = (float (*)[65])smraw;
      int b = pb >> 6;
      int n0 = (pb & 63) << 6;
      const float* pbp = points + ((size_t)b << 18);
      for (int i = tid; i < 4096; i += 256) {
        int cc = i >> 6, nn = i & 63;
        tile[cc][nn] = pbp[((size_t)cc << 12) + n0 + nn];
      }
      __syncthreads();
      for (int i = tid; i < 4096; i += 256) {
        int nn = i >> 6, cc = i & 63;
        pT[(((size_t)((b << 12) + n0 + nn)) << 6) + cc] = f2bf(tile[cc][nn]);
      }
    } else {
      // w0t: 64x104, w1t: 64x104, w2t: 128x104, stats: 512 floats
      for (int i = tid; i < 27136; i += 256) {
        if (i < 6656) {
          int nn = i / 104, kk = i % 104;
          float v = (kk < 64) ? W0[(3 + kk) * 64 + nn]
                              : ((kk < 67) ? W0[(kk - 64) * 64 + nn] : 0.f);
          w0t[i] = f2bf(v);
        } else if (i < 13312) {
          int j = i - 6656; int nn = j / 104, kk = j % 104;
          float v = (kk < 64) ? W1[kk * 64 + nn] : 0.f;
          w1t[j] = f2bf(v);
        } else if (i < 26624) {
          int j = i - 13312; int nn = j / 104, kk = j % 104;
          float v = (kk < 64) ? W2[kk * 128 + nn] : 0.f;
          w2t[j] = f2bf(v);
        } else {
          stats_all[i - 26624] = 0.f;
        }
      }
    }
    return;
  }
  // ---- FPS path ----
  float* xs  = (float*)smraw;                 // [4096]
  float* ys  = xs + 4096;                     // [4096]
  float* zs  = ys + 4096;                     // [4096]  (ends 49152 B)
  float* cxl = zs + 4096;                     // [1024]
  float* cyl = cxl + 1024;                    // [1024]
  float* czl = cyl + 1024;                    // [1024]  (ends 61440 B)
  unsigned long long (*keybuf)[4] =
      (unsigned long long (*)[4])(smraw + 61440);  // [2][4], 16B-aligned

  int b = blockIdx.x;
  const float* xb = xyz + (size_t)b * 12288;
  float px[16], py[16], pz[16], dist[16];
#pragma unroll
  for (int j = 0; j < 16; ++j) {
    int n = tid + (j << 8);
    px[j] = xb[n]; py[j] = xb[4096 + n]; pz[j] = xb[8192 + n];
    xs[n] = px[j]; ys[n] = py[j]; zs[n] = pz[j];
    dist[j] = 1e10f;
  }
  __syncthreads();
  float cx = xs[0], cy = ys[0], cz = zs[0];
  if (tid == 0) { cxl[0] = cx; cyl[0] = cy; czl[0] = cz; }
  int w = tid >> 6;
  int lane = tid & 63;
  for (int it = 1; it < 1024; ++it) {
    float bv = -1.f; int bi = 0;
#pragma unroll
    for (int j = 0; j < 16; ++j) {
      float dx = __fsub_rn(px[j], cx);
      float dy = __fsub_rn(py[j], cy);
      float dz = __fsub_rn(pz[j], cz);
      float d  = __fadd_rn(__fadd_rn(__fmul_rn(dx, dx), __fmul_rn(dy, dy)),
                           __fmul_rn(dz, dz));
      float nd = fminf(dist[j], d);
      dist[j] = nd;
      if (nd > bv) { bv = nd; bi = tid + (j << 8); }  // strict >, j asc => min n
    }
    // pack: high 32 = dist bits (nonneg float => monotone), low 32 = ~n
    unsigned long long k =
        ((unsigned long long)__float_as_uint(bv) << 32) | (unsigned)(~bi);
    k = dppmax<0xB1>(k);    // quad_perm [1,0,3,2]  : xor 1
    k = dppmax<0x4E>(k);    // quad_perm [2,3,0,1]  : xor 2
    k = dppmax<0x141>(k);   // row_half_mirror      : xor 4
    k = dppmax<0x140>(k);   // row_mirror           : xor 8
    k = dppmax<0x142>(k);   // row_bcast15          : rows 0->1, 2->3
    k = dppmax<0x143>(k);   // row_bcast31          : rows 01 -> 23
    int p = it & 1;
    if (lane == 63) keybuf[p][w] = k;   // lane63 holds the wave max
    __syncthreads();
    // combine 4 wave keys: 2x b128 reads + 3-compare tree (uniform)
    uint4 ka2 = *(const uint4*)&keybuf[p][0];
    uint4 kb2 = *(const uint4*)&keybuf[p][2];
    unsigned long long k0 = ((unsigned long long)ka2.y << 32) | ka2.x;
    unsigned long long k1 = ((unsigned long long)ka2.w << 32) | ka2.z;
    unsigned long long k2 = ((unsigned long long)kb2.y << 32) | kb2.x;
    unsigned long long k3 = ((unsigned long long)kb2.w << 32) | kb2.z;
    unsigned long long m01 = (k1 > k0) ? k1 : k0;
    unsigned long long m23 = (k3 > k2) ? k3 : k2;
    unsigned long long km  = (m23 > m01) ? m23 : m01;
    int gi = (int)(~(unsigned)km) & 4095;
    cx = xs[gi]; cy = ys[gi]; cz = zs[gi];
    if (tid == 0) { cxl[it] = cx; cyl[it] = cy; czl[it] = cz; }
    // no second barrier: next iter writes keybuf[(it+1)&1], disjoint slot;
    // a wave re-writes this slot only after passing the NEXT barrier, which
    // orders it after every wave's read above.
  }
  __syncthreads();
  for (int it = tid; it < 1024; it += 256) {
    float x = cxl[it], y = cyl[it], z = czl[it];
    out[b * 3072 + it]        = x;
    out[b * 3072 + 1024 + it] = y;
    out[b * 3072 + 2048 + it] = z;
    centers4[(b << 10) + it]  = make_float4(x, y, z, 0.f);
  }
}

// ---------------------------------------------------------------------------
// Ball query, wave-per-center (round 7 rewrite). Old version: thread-per-
// center serial scan over all 4096 points; with 64 blocks -> 1 wave/SIMD the
// ~120cyc LDS broadcast latency chained per point: 4096 x ~150cyc ~= 630us
// (FPS picks boundary points whose low hit density forces full scans).
// New: each wave scans 64 points/chunk for ONE center; __ballot(hit) +
// prefix popcount assigns ranks; ranks <32 store (ascending n => identical
// to the reference's sort-then-take-32). Early exit per wave when cnt>=32.
// 64 chunks max vs 4096 serial steps, and 256 blocks for occupancy.
// ---------------------------------------------------------------------------
__global__ __launch_bounds__(256) void ball_kernel(const float* __restrict__ xyz,
                                                   const float4* __restrict__ centers4,
                                                   int* __restrict__ ballidx)
{
  __shared__ float xs[4096], ys[4096], zs[4096];
  int tid = threadIdx.x;
  int b = blockIdx.x >> 4;          // 16 blocks per batch
  int g = blockIdx.x & 15;          // 64-center group within batch
  const float* xb = xyz + (size_t)b * 12288;
  for (int i = tid; i < 4096; i += 256) {
    xs[i] = xb[i]; ys[i] = xb[4096 + i]; zs[i] = xb[8192 + i];
  }
  __syncthreads();
  int w = tid >> 6, lane = tid & 63;
  unsigned long long lmask = (1ull << lane) - 1ull;
  for (int j = 0; j < 16; ++j) {
    int s = (g << 6) + (j << 2) + w;          // wave-interleaved centers
    float4 c = centers4[(b << 10) + s];
    int* ob = ballidx + (((size_t)((b << 10) + s)) << 5);
    int cnt = 0, first = 0;
    for (int m = 0; m < 64; ++m) {
      int n = (m << 6) + lane;
      float dx = __fsub_rn(xs[n], c.x);
      float dy = __fsub_rn(ys[n], c.y);
      float dz = __fsub_rn(zs[n], c.z);
      float d  = __fadd_rn(__fadd_rn(__fmul_rn(dx, dx), __fmul_rn(dy, dy)),
                           __fmul_rn(dz, dz));
      bool hit = !(d > 0.04f);      // 0.04f == f32(RADIUS**2), matches ref
      unsigned long long mask = __ballot(hit);
      if (cnt == 0 && mask != 0ull)
        first = (m << 6) + (__ffsll((long long)mask) - 1);
      int p = cnt + (int)__popcll(mask & lmask);
      if (hit && p < 32) ob[p] = n;
      cnt += (int)__popcll(mask);
      if (cnt >= 32) break;
    }
    // tail fill (cnt uniform across the wave; center itself always hits so cnt>=1)
    if (lane < 32 && lane >= cnt) ob[lane] = first;
  }
}

// ---------------------------------------------------------------------------
// GEMM1: gather (pT rows + g_xyz) -> A[64 x 96(pad104)] bf16, W'T0, MFMA,
// write raw y1 bf16 [M,64] + per-block channel partials (sum, sumsq).
// ---------------------------------------------------------------------------
__global__ __launch_bounds__(256) void gemm1_kernel(
    const float* __restrict__ xyz, const unsigned short* __restrict__ pT,
    const unsigned short* __restrict__ w0t, const float* __restrict__ b0,
    const float4* __restrict__ centers4, const int* __restrict__ ballidx,
    unsigned short* __restrict__ feats1, float* __restrict__ partials)
{
  __shared__ unsigned short As[64 * LDA];
  __shared__ unsigned short Wt[64 * LDA];
  __shared__ float red[2][4][64];
  int tid = threadIdx.x;
  int rowbase = blockIdx.x << 6;
  int b = rowbase >> 15;
  {
    const uint4* wsrc = (const uint4*)w0t;
    uint4* wdst = (uint4*)Wt;
    for (int i = tid; i < 832; i += 256) wdst[i] = wsrc[i];
  }
  {
    int rl = tid >> 2, part = tid & 3;
    int r = rowbase + rl;
    int n = ballidx[r];
    const uint4* psrc = (const uint4*)(pT + (((size_t)((b << 12) + n)) << 6));
    uint4* adst = (uint4*)(As + rl * LDA);
    adst[part * 2]     = psrc[part * 2];
    adst[part * 2 + 1] = psrc[part * 2 + 1];
    adst[8 + part] = make_uint4(0, 0, 0, 0);   // zero cols 64..95
    if (part == 0) {
      int ci = r >> 5;
      float4 c = centers4[ci];
      unsigned short* arow = As + rl * LDA;
      arow[64] = f2bf(__fsub_rn(xyz[(size_t)b * 12288 + n],        c.x));
      arow[65] = f2bf(__fsub_rn(xyz[(size_t)b * 12288 + 4096 + n], c.y));
      arow[66] = f2bf(__fsub_rn(xyz[(size_t)b * 12288 + 8192 + n], c.z));
    }
  }
  __syncthreads();
  int lane = tid & 63, w = tid >> 6;
  int mrow = (w << 4) + (lane & 15);
  int quad = lane >> 4;
  f32x4 acc[4];
#pragma unroll
  for (int nt = 0; nt < 4; ++nt) acc[nt] = (f32x4){0.f, 0.f, 0.f, 0.f};
#pragma unroll
  for (int kt = 0; kt < 3; ++kt) {
    int ko = kt * 32 + (quad << 3);
    bf16x8 a = *(const bf16x8*)(As + mrow * LDA + ko);
#pragma unroll
    for (int nt = 0; nt < 4; ++nt) {
      bf16x8 bb = *(const bf16x8*)(Wt + ((nt << 4) + (lane & 15)) * LDA + ko);
      acc[nt] = __builtin_amdgcn_mfma_f32_16x16x32_bf16(a, bb, acc[nt], 0, 0, 0);
    }
  }
#pragma unroll
  for (int nt = 0; nt < 4; ++nt) {
    int cch = (nt << 4) + (lane & 15);
    float bias = b0[cch];
    float ssum = 0.f, sq = 0.f;
#pragma unroll
    for (int r2 = 0; r2 < 4; ++r2) {
      float y = acc[nt][r2] + bias;
      int ml = (w << 4) + (quad << 2) + r2;
      feats1[(((size_t)(rowbase + ml)) << 6) + cch] = f2bf(y);
      ssum += y; sq += y * y;
    }
    ssum += __shfl_xor(ssum, 16); ssum += __shfl_xor(ssum, 32);
    sq   += __shfl_xor(sq, 16);   sq   += __shfl_xor(sq, 32);
    if (quad == 0) { red[0][w][cch] = ssum; red[1][w][cch] = sq; }
  }
  __syncthreads();
  if (tid < 64) {
    float a0 = red[0][0][tid] + red[0][1][tid] + red[0][2][tid] + red[0][3][tid];
    float a1 = red[1][0][tid] + red[1][1][tid] + red[1][2][tid] + red[1][3][tid];
    partials[(size_t)blockIdx.x * 256 + tid]      = a0;
    partials[(size_t)blockIdx.x * 256 + 64 + tid] = a1;
  }
}

// ---------------------------------------------------------------------------
// GEMM2: A = relu(scale*y1+shift) from feats1; K=64; out raw y2 + partials.
// ---------------------------------------------------------------------------
__global__ __launch_bounds__(256) void gemm2_kernel(
    const unsigned short* __restrict__ featsIn, const unsigned short* __restrict__ wt,
    const float* __restrict__ bias_g, const float* __restrict__ ss_in,
    unsigned short* __restrict__ featsOut, float* __restrict__ partials)
{
  __shared__ unsigned short As[64 * LDA];
  __shared__ unsigned short Wt[64 * LDA];
  __shared__ float red[2][4][64];
  __shared__ float ssl[128];
  int tid = threadIdx.x;
  int rowbase = blockIdx.x << 6;
  if (tid < 128) ssl[tid] = ss_in[tid];
  {
    const uint4* wsrc = (const uint4*)wt;
    uint4* wdst = (uint4*)Wt;
    for (int i = tid; i < 832; i += 256) wdst[i] = wsrc[i];
  }
  __syncthreads();
  {
    int rl = tid >> 2, part = tid & 3;
    size_t r = (size_t)rowbase + rl;
    union { uint4 v[2]; unsigned short u[16]; } t;
    const uint4* src = (const uint4*)(featsIn + (r << 6));
    t.v[0] = src[part * 2]; t.v[1] = src[part * 2 + 1];
    union { uint4 v[2]; unsigned short u[16]; } o;
#pragma unroll
    for (int e = 0; e < 16; ++e) {
      int cch = (part << 4) + e;
      float f = bf2f(t.u[e]);
      float y = fmaxf(f * ssl[cch] + ssl[64 + cch], 0.f);
      o.u[e] = f2bf(y);
    }
    uint4* adst = (uint4*)(As + rl * LDA + (part << 4));
    adst[0] = o.v[0]; adst[1] = o.v[1];
  }
  __syncthreads();
  int lane = tid & 63, w = tid >> 6;
  int mrow = (w << 4) + (lane & 15);
  int quad = lane >> 4;
  f32x4 acc[4];
#pragma unroll
  for (int nt = 0; nt < 4; ++nt) acc[nt] = (f32x4){0.f, 0.f, 0.f, 0.f};
#pragma unroll
  for (int kt = 0; kt < 2; ++kt) {
    int ko = kt * 32 + (quad << 3);
    bf16x8 a = *(const bf16x8*)(As + mrow * LDA + ko);
#pragma unroll
    for (int nt = 0; nt < 4; ++nt) {
      bf16x8 bb = *(const bf16x8*)(Wt + ((nt << 4) + (lane & 15)) * LDA + ko);
      acc[nt] = __builtin_amdgcn_mfma_f32_16x16x32_bf16(a, bb, acc[nt], 0, 0, 0);
    }
  }
#pragma unroll
  for (int nt = 0; nt < 4; ++nt) {
    int cch = (nt << 4) + (lane & 15);
    float bias = bias_g[cch];
    float ssum = 0.f, sq = 0.f;
#pragma unroll
    for (int r2 = 0; r2 < 4; ++r2) {
      float y = acc[nt][r2] + bias;
      int ml = (w << 4) + (quad << 2) + r2;
      featsOut[(((size_t)(rowbase + ml)) << 6) + cch] = f2bf(y);
      ssum += y; sq += y * y;
    }
    ssum += __shfl_xor(ssum, 16); ssum += __shfl_xor(ssum, 32);
    sq   += __shfl_xor(sq, 16);   sq   += __shfl_xor(sq, 32);
    if (quad == 0) { red[0][w][cch] = ssum; red[1][w][cch] = sq; }
  }
  __syncthreads();
  if (tid < 64) {
    float a0 = red[0][0][tid] + red[0][1][tid] + red[0][2][tid] + red[0][3][tid];
    float a1 = red[1][0][tid] + red[1][1][tid] + red[1][2][tid] + red[1][3][tid];
    partials[(size_t)blockIdx.x * 256 + tid]      = a0;
    partials[(size_t)blockIdx.x * 256 + 64 + tid] = a1;
  }
}

// ---------------------------------------------------------------------------
// GEMM3 stats pass: y3 = relu2(feats2)@W2 + b2 ; only channel partials, no store.
// ---------------------------------------------------------------------------
__global__ __launch_bounds__(256) void gemm3_stats_kernel(
    const unsigned short* __restrict__ feats2, const unsigned short* __restrict__ w2t,
    const float* __restrict__ b2, const float* __restrict__ ss2,
    float* __restrict__ partials)
{
  __shared__ unsigned short As[64 * LDA];
  __shared__ unsigned short Wt[128 * LDA];
  __shared__ float red[2][4][128];
  __shared__ float ssl[128];
  int tid = threadIdx.x;
  int rowbase = blockIdx.x << 6;
  if (tid < 128) ssl[tid] = ss2[tid];
  {
    const uint4* wsrc = (const uint4*)w2t;
    uint4* wdst = (uint4*)Wt;
    for (int i = tid; i < 1664; i += 256) wdst[i] = wsrc[i];
  }
  __syncthreads();
  {
    int rl = tid >> 2, part = tid & 3;
    size_t r = (size_t)rowbase + rl;
    union { uint4 v[2]; unsigned short u[16]; } t;
    const uint4* src = (const uint4*)(feats2 + (r << 6));
    t.v[0] = src[part * 2]; t.v[1] = src[part * 2 + 1];
    union { uint4 v[2]; unsigned short u[16]; } o;
#pragma unroll
    for (int e = 0; e < 16; ++e) {
      int cch = (part << 4) + e;
      float f = bf2f(t.u[e]);
      float y = fmaxf(f * ssl[cch] + ssl[64 + cch], 0.f);
      o.u[e] = f2bf(y);
    }
    uint4* adst = (uint4*)(As + rl * LDA + (part << 4));
    adst[0] = o.v[0]; adst[1] = o.v[1];
  }
  __syncthreads();
  int lane = tid & 63, w = tid >> 6;
  int mrow = (w << 4) + (lane & 15);
  int quad = lane >> 4;
  f32x4 acc[8];
#pragma unroll
  for (int nt = 0; nt < 8; ++nt) acc[nt] = (f32x4){0.f, 0.f, 0.f, 0.f};
#pragma unroll
  for (int kt = 0; kt < 2; ++kt) {
    int ko = kt * 32 + (quad << 3);
    bf16x8 a = *(const bf16x8*)(As + mrow * LDA + ko);
#pragma unroll
    for (int nt = 0; nt < 8; ++nt) {
      bf16x8 bb = *(const bf16x8*)(Wt + ((nt << 4) + (lane & 15)) * LDA + ko);
      acc[nt] = __builtin_amdgcn_mfma_f32_16x16x32_bf16(a, bb, acc[nt], 0, 0, 0);
    }
  }
#pragma unroll
  for (int nt = 0; nt < 8; ++nt) {
    int cch = (nt << 4) + (lane & 15);
    float bias = b2[cch];
    float ssum = 0.f, sq = 0.f;
#pragma unroll
    for (int r2 = 0; r2 < 4; ++r2) {
      float y = acc[nt][r2] + bias;
      ssum += y; sq += y * y;
    }
    ssum += __shfl_xor(ssum, 16); ssum += __shfl_xor(ssum, 32);
    sq   += __shfl_xor(sq, 16);   sq   += __shfl_xor(sq, 32);
    if (quad == 0) { red[0][w][cch] = ssum; red[1][w][cch] = sq; }
  }
  __syncthreads();
  if (tid < 128) {
    float a0 = red[0][0][tid] + red[0][1][tid] + red[0][2][tid] + red[0][3][tid];
    float a1 = red[1][0][tid] + red[1][1][tid] + red[1][2][tid] + red[1][3][tid];
    partials[(size_t)blockIdx.x * 256 + tid]       = a0;
    partials[(size_t)blockIdx.x * 256 + 128 + tid] = a1;
  }
}

// ---------------------------------------------------------------------------
// Final: recompute y3, apply BN3+relu, max over K=32, write [B,S,128] compact.
// ---------------------------------------------------------------------------
__global__ __launch_bounds__(256) void final_kernel(
    const unsigned short* __restrict__ feats2, const unsigned short* __restrict__ w2t,
    const float* __restrict__ b2, const float* __restrict__ ss2,
    const float* __restrict__ ss3, float* __restrict__ out_tmp)
{
  __shared__ unsigned short As[64 * LDA];
  __shared__ unsigned short Wt[128 * LDA];
  __shared__ float ssl[128];
  __shared__ unsigned mx[2][128];
  int tid = threadIdx.x;
  int rowbase = blockIdx.x << 6;
  if (tid < 128) ssl[tid] = ss2[tid];
  ((unsigned*)mx)[tid] = 0u;   // relu outputs >= 0, so 0 == -inf here
  {
    const uint4* wsrc = (const uint4*)w2t;
    uint4* wdst = (uint4*)Wt;
    for (int i = tid; i < 1664; i += 256) wdst[i] = wsrc[i];
  }
  __syncthreads();
  {
    int rl = tid >> 2, part = tid & 3;
    size_t r = (size_t)rowbase + rl;
    union { uint4 v[2]; unsigned short u[16]; } t;
    const uint4* src = (const uint4*)(feats2 + (r << 6));
    t.v[0] = src[part * 2]; t.v[1] = src[part * 2 + 1];
    union { uint4 v[2]; unsigned short u[16]; } o;
#pragma unroll
    for (int e = 0; e < 16; ++e) {
      int cch = (part << 4) + e;
      float f = bf2f(t.u[e]);
      float y = fmaxf(f * ssl[cch] + ssl[64 + cch], 0.f);
      o.u[e] = f2bf(y);
    }
    uint4* adst = (uint4*)(As + rl * LDA + (part << 4));
    adst[0] = o.v[0]; adst[1] = o.v[1];
  }
  __syncthreads();
  int lane = tid & 63, w = tid >> 6;
  int mrow = (w << 4) + (lane & 15);
  int quad = lane >> 4;
  f32x4 acc[8];
#pragma unroll
  for (int nt = 0; nt < 8; ++nt) acc[nt] = (f32x4){0.f, 0.f, 0.f, 0.f};
#pragma unroll
  for (int kt = 0; kt < 2; ++kt) {
    int ko = kt * 32 + (quad << 3);
    bf16x8 a = *(const bf16x8*)(As + mrow * LDA + ko);
#pragma unroll
    for (int nt = 0; nt < 8; ++nt) {
      bf16x8 bb = *(const bf16x8*)(Wt + ((nt << 4) + (lane & 15)) * LDA + ko);
      acc[nt] = __builtin_amdgcn_mfma_f32_16x16x32_bf16(a, bb, acc[nt], 0, 0, 0);
    }
  }
  int cloc = w >> 1;   // rows 0..31 -> center 0, rows 32..63 -> center 1
#pragma unroll
  for (int nt = 0; nt < 8; ++nt) {
    int cch = (nt << 4) + (lane & 15);
    float bias = b2[cch];
    float sc = ss3[cch], sh = ss3[128 + cch];
    float m = 0.f;
#pragma unroll
    for (int r2 = 0; r2 < 4; ++r2) {
      float y = acc[nt][r2] + bias;
      float tv = fmaxf(y * sc + sh, 0.f);
      m = fmaxf(m, tv);
    }
    atomicMax(&mx[cloc][cch], __float_as_uint(m));
  }
  __syncthreads();
  {
    int c2 = tid >> 7, cch = tid & 127;
    float v = __uint_as_float(mx[c2][cch]);
    int cg = (rowbase >> 5) + c2;            // global center index b*1024+s
    out_tmp[((size_t)cg << 7) + cch] = v;
  }
}

// ---------------------------------------------------------------------------
// stats reduce + finalize
// ---------------------------------------------------------------------------
__global__ __launch_bounds__(256) void reduce_kernel(const float* __restrict__ partials,
                                                     float* __restrict__ stats, int twoC)
{
  int tid = threadIdx.x;
  if (tid < twoC) {
    int row0 = blockIdx.x << 7;
    float s = 0.f;
    for (int r = 0; r < 128; ++r) s += partials[((size_t)(row0 + r)) * 256 + tid];
    atomicAdd(&stats[tid], s);
  }
}

__global__ void finalize_kernel(const float* __restrict__ stats, const float* __restrict__ g,
                                const float* __restrict__ be, float* __restrict__ ss, int C)
{
  int c = threadIdx.x;
  if (c < C) {
    const float invM = 1.f / 524288.f;
    float mean = stats[c] * invM;
    float ex2  = stats[C + c] * invM;
    float var  = ex2 - mean * mean;
    float sc   = g[c] / sqrtf(var + 1e-5f);
    ss[c]     = sc;
    ss[C + c] = be[c] - mean * sc;
  }
}

// ---------------------------------------------------------------------------
// out_tmp [B,S,128] -> d_out [B,128,S] (offset 49152)
// ---------------------------------------------------------------------------
__global__ __launch_bounds__(256) void transpose_out_kernel(const float* __restrict__ out_tmp,
                                                            float* __restrict__ out)
{
  __shared__ float t2[64][65];
  int tid = threadIdx.x;
  int b = blockIdx.x >> 5;
  int rest = blockIdx.x & 31;
  int s0 = (rest & 15) << 6;
  int c0 = (rest >> 4) << 6;
  for (int i = tid; i < 4096; i += 256) {
    int row = i >> 6, col = i & 63;
    t2[row][col] = out_tmp[((size_t)((b << 10) + s0 + row)) * 128 + c0 + col];
  }
  __syncthreads();
  for (int i = tid; i < 4096; i += 256) {
    int crow = i >> 6, scol = i & 63;
    out[49152 + ((size_t)b << 17) + (size_t)(c0 + crow) * 1024 + s0 + scol] = t2[scol][crow];
  }
}

// ---------------------------------------------------------------------------
extern "C" void kernel_launch(void* const* d_in, const int* in_sizes, int n_in,
                              void* d_out, int out_size, void* d_ws, size_t ws_size,
                              hipStream_t stream)
{
  (void)in_sizes; (void)n_in; (void)out_size; (void)ws_size;
  const float* xyz    = (const float*)d_in[0];
  const float* points = (const float*)d_in[1];
  const float* W0  = (const float*)d_in[2];
  const float* b0  = (const float*)d_in[3];
  const float* g0  = (const float*)d_in[4];
  const float* be0 = (const float*)d_in[5];
  const float* W1  = (const float*)d_in[6];
  const float* b1  = (const float*)d_in[7];
  const float* g1  = (const float*)d_in[8];
  const float* be1 = (const float*)d_in[9];
  const float* W2  = (const float*)d_in[10];
  const float* b2  = (const float*)d_in[11];
  const float* g2  = (const float*)d_in[12];
  const float* be2 = (const float*)d_in[13];
  float* out = (float*)d_out;

  char* base = (char*)d_ws;
  size_t off = 0;
  auto alloc = [&](size_t bytes) -> void* {
    void* p = base + off;
    off += (bytes + 255) & ~(size_t)255;
    return p;
  };
  unsigned short* pT     = (unsigned short*)alloc((size_t)16 * 4096 * 64 * 2);
  unsigned short* w0t    = (unsigned short*)alloc(64 * LDA * 2);
  unsigned short* w1t    = (unsigned short*)alloc(64 * LDA * 2);
  unsigned short* w2t    = (unsigned short*)alloc(128 * LDA * 2);
  float* stats_all       = (float*)alloc(512 * 4);
  float* ss_all          = (float*)alloc(512 * 4);
  float4* centers4       = (float4*)alloc((size_t)16 * 1024 * 16);
  int* ballidx           = (int*)alloc((size_t)16 * 1024 * 32 * 4);
  unsigned short* feats1 = (unsigned short*)alloc((size_t)524288 * 64 * 2);
  unsigned short* feats2 = (unsigned short*)alloc((size_t)524288 * 64 * 2);
  float* partials        = (float*)alloc((size_t)8192 * 256 * 4);
  float* out_tmp         = (float*)alloc((size_t)16 * 1024 * 128 * 4);

  float* stats1 = stats_all;       float* stats2 = stats_all + 128; float* stats3 = stats_all + 256;
  float* ss1 = ss_all;             float* ss2 = ss_all + 128;       float* ss3 = ss_all + 256;

  fps_prep_kernel<<<1041, 256, 0, stream>>>(xyz, points, W0, W1, W2, pT, w0t, w1t,
                                            w2t, stats_all, out, centers4);
  ball_kernel<<<256, 256, 0, stream>>>(xyz, centers4, ballidx);
  gemm1_kernel<<<8192, 256, 0, stream>>>(xyz, pT, w0t, b0, centers4, ballidx, feats1, partials);
  reduce_kernel<<<64, 256, 0, stream>>>(partials, stats1, 128);
  finalize_kernel<<<1, 64, 0, stream>>>(stats1, g0, be0, ss1, 64);
  gemm2_kernel<<<8192, 256, 0, stream>>>(feats1, w1t, b1, ss1, feats2, partials);
  reduce_kernel<<<64, 256, 0, stream>>>(partials, stats2, 128);
  finalize_kernel<<<1, 64, 0, stream>>>(stats2, g1, be1, ss2, 64);
  gemm3_stats_kernel<<<8192, 256, 0, stream>>>(feats2, w2t, b2, ss2, partials);
  reduce_kernel<<<64, 256, 0, stream>>>(partials, stats3, 256);
  finalize_kernel<<<1, 128, 0, stream>>>(stats3, g2, be2, ss3, 128);
  final_kernel<<<8192, 256, 0, stream>>>(feats2, w2t, b2, ss2, ss3, out_tmp);
  transpose_out_kernel<<<512, 256, 0, stream>>>(out_tmp, out);
}